// Round 13
// baseline (235.098 us; speedup 1.0000x reference)
//
#include <hip/hip_runtime.h>
#include <stdint.h>

#define NN 8192       // nodes
#define WPR 256       // u32 words per bitmask row (8192 bits)
#define CSTRIDE 192   // CSR slots/row; P[deg>192] ~ 1e-40 for Poisson(64); writes guarded

typedef _Float16 f16;
typedef f16 f16x2 __attribute__((ext_vector_type(2)));
typedef f16 f16x4 __attribute__((ext_vector_type(4)));
typedef f16 f16x8 __attribute__((ext_vector_type(8)));
typedef float f32x4 __attribute__((ext_vector_type(4)));

// ---------------------------------------------------------------------------
// Adjacency bitmask: set semantics (duplicates collapse) via atomicOr
// ---------------------------------------------------------------------------
__global__ __launch_bounds__(256) void build_adj(const int* __restrict__ ei,
                                                 uint32_t* __restrict__ mask,
                                                 int E) {
  int t = blockIdx.x * blockDim.x + threadIdx.x;
  if (t >= E) return;
  int a = ei[t];        // e0
  int b = ei[E + t];    // e1
  atomicOr(&mask[(size_t)a * WPR + (b >> 5)], 1u << (b & 31));
  atomicOr(&mask[(size_t)b * WPR + (a >> 5)], 1u << (a & 31));
}

// ---------------------------------------------------------------------------
// Bitmask -> fixed-stride CSR (uint16 ids) + dinv. One wave per row. Self-edge
// bit stays (diag=2 case); eye handled separately in spmm. dinv=rsqrt(pop+1).
// ---------------------------------------------------------------------------
__global__ __launch_bounds__(256) void mask_to_csr(const uint32_t* __restrict__ mask,
                                                   uint16_t* __restrict__ cols,
                                                   int* __restrict__ nnz,
                                                   float* __restrict__ dinv) {
  const int row = blockIdx.x * 4 + (threadIdx.x >> 6);
  const int lane = threadIdx.x & 63;
  const uint4 w = ((const uint4*)(mask + (size_t)row * WPR))[lane];
  const int c = __popc(w.x) + __popc(w.y) + __popc(w.z) + __popc(w.w);
  int inc = c;
#pragma unroll
  for (int o = 1; o < 64; o <<= 1) {
    int v = __shfl_up(inc, o);
    if (lane >= o) inc += v;
  }
  const int total = __shfl(inc, 63);
  int base = row * CSTRIDE + (inc - c);
  const int lim = row * CSTRIDE + CSTRIDE;
  uint32_t ws_[4] = {w.x, w.y, w.z, w.w};
#pragma unroll
  for (int i = 0; i < 4; ++i) {
    uint32_t word = ws_[i];
    int boff = (lane * 4 + i) << 5;
    while (word) {
      int b = __ffs(word) - 1;
      word &= word - 1;
      if (base < lim) cols[base] = (uint16_t)(boff + b);
      ++base;
    }
  }
  if (lane == 0) {
    nnz[row] = (total > CSTRIDE) ? CSTRIDE : total;
    dinv[row] = rsqrtf((float)(total + 1));
  }
}

// ---------------------------------------------------------------------------
// One-shot prep:
//  blocks 0..639   : W fp32 [K][N] -> Wt f16 [N][K] (32x32 LDS transpose)
//  blocks 640..2687: x fp32 -> Xh f16 straight copy (8 elems/thread)
// ---------------------------------------------------------------------------
__global__ __launch_bounds__(256) void prep_all(const float* __restrict__ W1,
                                                const float* __restrict__ W2,
                                                const float* __restrict__ W3,
                                                const float* __restrict__ x,
                                                f16* __restrict__ T1,
                                                f16* __restrict__ T2,
                                                f16* __restrict__ T3,
                                                f16* __restrict__ Xh) {
  int tile = blockIdx.x;
  if (tile >= 640) {  // x convert: 2048 elems per block
    size_t base = (size_t)(tile - 640) * 2048 + threadIdx.x * 8;
    float4 v0 = *(const float4*)&x[base];
    float4 v1 = *(const float4*)&x[base + 4];
    f16x8 h = {(f16)v0.x, (f16)v0.y, (f16)v0.z, (f16)v0.w,
               (f16)v1.x, (f16)v1.y, (f16)v1.z, (f16)v1.w};
    *(f16x8*)&Xh[base] = h;
    return;
  }
  const float* W; f16* T; int N;
  if (tile < 256)      { W = W1; T = T1; N = 512; }
  else if (tile < 512) { W = W2; T = T2; N = 512; tile -= 256; }
  else                 { W = W3; T = T3; N = 256; tile -= 512; }
  const int K = 512;
  const int ntn = N >> 5;
  const int k0 = (tile / ntn) << 5, n0 = (tile % ntn) << 5;
  __shared__ f16 tl[32][33];
  const int tx = threadIdx.x & 31, ty = threadIdx.x >> 5;
#pragma unroll
  for (int r = 0; r < 32; r += 8)
    tl[ty + r][tx] = (f16)W[(size_t)(k0 + ty + r) * N + n0 + tx];
  __syncthreads();
#pragma unroll
  for (int r = 0; r < 32; r += 8)
    T[(size_t)(n0 + ty + r) * K + k0 + tx] = tl[tx][ty + r];
}

// ---------------------------------------------------------------------------
// Panel-resident f16-MFMA GEMM: Ys[m,:] = (f16)( rs[m] * (A@Wt^T)[m,:] )
// A f16 [M,512]; Wt f16 [N][512]. BM=32, grid=M/32=256 blocks (1/CU).
// Stage the block's FULL 32x512 A-panel in 32 KB LDS ONCE (single barrier);
// K-loop has NO barriers: A frags from LDS, B frags direct from global
// (Wt is <=0.5 MB, L2-resident; latency hidden under 16 MFMAs/step + ILP).
// 4 waves; wave w covers all 32 rows x cols [w*N/4, (w+1)*N/4).
// Fragment layout (validated R5-R12): A row=lane&15, k=(lane>>4)*8+j;
// B col=lane&15, same k; D row=(lane>>4)*4+r, col=lane&15.
// ---------------------------------------------------------------------------
template <int N>
__global__ __launch_bounds__(256) void gemm_panel(const f16* __restrict__ A,
                                                  const f16* __restrict__ Wt,
                                                  const float* __restrict__ rs,
                                                  f16* __restrict__ Ys) {
  constexpr int K = 512;
  constexpr int NF = N / 64;           // 16-col fragments per wave (8 or 4)
  __shared__ f16 As[32 * K];           // 32 KB, linear [row][k]
  const int t = threadIdx.x;
  const int lane = t & 63;
  const int w = t >> 6;
  const int lm = lane & 15, kg = lane >> 4;
  const int m0 = blockIdx.x * 32;
  const int n0w = w * (N / 4);

  // stage A panel once: 32x512 f16 = 4096 f16x8, 8 per thread
#pragma unroll
  for (int i = 0; i < 8; ++i) {
    int idx = i * 256 + t;
    *(f16x8*)&As[idx * 8] = *(const f16x8*)&A[(size_t)m0 * K + idx * 8];
  }
  __syncthreads();   // the ONLY barrier

  f32x4 acc[2][NF] = {};
#pragma unroll 4
  for (int k0 = 0; k0 < K; k0 += 32) {
    f16x8 af[2];
#pragma unroll
    for (int mf = 0; mf < 2; ++mf)
      af[mf] = *(const f16x8*)&As[(mf * 16 + lm) * K + k0 + kg * 8];
    f16x8 bf[NF];
#pragma unroll
    for (int nf = 0; nf < NF; ++nf)
      bf[nf] = *(const f16x8*)&Wt[(size_t)(n0w + nf * 16 + lm) * K + k0 + kg * 8];
#pragma unroll
    for (int mf = 0; mf < 2; ++mf)
#pragma unroll
      for (int nf = 0; nf < NF; ++nf)
        acc[mf][nf] = __builtin_amdgcn_mfma_f32_16x16x32_f16(af[mf], bf[nf], acc[mf][nf], 0, 0, 0);
  }

  // epilogue: row-scale by rs, convert f16, store
#pragma unroll
  for (int mf = 0; mf < 2; ++mf) {
#pragma unroll
    for (int r = 0; r < 4; ++r) {
      int row = m0 + mf * 16 + kg * 4 + r;
      float s = rs[row];
#pragma unroll
      for (int nf = 0; nf < NF; ++nf) {
        int col = n0w + nf * 16 + lm;
        Ys[(size_t)row * N + col] = (f16)(s * acc[mf][nf][r]);
      }
    }
  }
}

// ---------------------------------------------------------------------------
// Column-chunked CSR SpMM (at its L2 random-gather floor per R11/R12 nulls).
// chunk = blockIdx % Q (Q = NC/128, 2 MB chunks -> XCD-L2-resident). Block =
// 4 rows; one wave per row; lane covers 2 cols (f16x2); 16 independent
// gathers in flight; packed f16x2 tree-sum, fp32 flush.
// ---------------------------------------------------------------------------
template <int NC, typename OutT, bool RELU>
__global__ __launch_bounds__(256) void spmm_csr(const uint16_t* __restrict__ cols,
                                                const int* __restrict__ nnz,
                                                const float* __restrict__ dinv,
                                                const f16* __restrict__ Ys,
                                                const float* __restrict__ bias,
                                                OutT* __restrict__ out) {
  constexpr int Q = NC / 128;
  const int b = blockIdx.x;
  const int chunk = b % Q;
  const int rg = b / Q;
  const int w = threadIdx.x >> 6, lane = threadIdx.x & 63;
  const int row = rg * 4 + w;
  const int cb = chunk * 128 + 2 * lane;

  __shared__ uint16_t cidx[4][CSTRIDE];
  const int n = nnz[row];
  for (int k = lane; k < n; k += 64) cidx[w][k] = cols[row * CSTRIDE + k];
  __syncthreads();

  const f16* __restrict__ Yc = Ys + cb;
  float a0 = 0.f, a1 = 0.f;
  int k = 0;
  for (; k + 16 <= n; k += 16) {
    f16x2 v0  = *(const f16x2*)&Yc[(size_t)cidx[w][k + 0]  * NC];
    f16x2 v1  = *(const f16x2*)&Yc[(size_t)cidx[w][k + 1]  * NC];
    f16x2 v2  = *(const f16x2*)&Yc[(size_t)cidx[w][k + 2]  * NC];
    f16x2 v3  = *(const f16x2*)&Yc[(size_t)cidx[w][k + 3]  * NC];
    f16x2 v4  = *(const f16x2*)&Yc[(size_t)cidx[w][k + 4]  * NC];
    f16x2 v5  = *(const f16x2*)&Yc[(size_t)cidx[w][k + 5]  * NC];
    f16x2 v6  = *(const f16x2*)&Yc[(size_t)cidx[w][k + 6]  * NC];
    f16x2 v7  = *(const f16x2*)&Yc[(size_t)cidx[w][k + 7]  * NC];
    f16x2 v8  = *(const f16x2*)&Yc[(size_t)cidx[w][k + 8]  * NC];
    f16x2 v9  = *(const f16x2*)&Yc[(size_t)cidx[w][k + 9]  * NC];
    f16x2 v10 = *(const f16x2*)&Yc[(size_t)cidx[w][k + 10] * NC];
    f16x2 v11 = *(const f16x2*)&Yc[(size_t)cidx[w][k + 11] * NC];
    f16x2 v12 = *(const f16x2*)&Yc[(size_t)cidx[w][k + 12] * NC];
    f16x2 v13 = *(const f16x2*)&Yc[(size_t)cidx[w][k + 13] * NC];
    f16x2 v14 = *(const f16x2*)&Yc[(size_t)cidx[w][k + 14] * NC];
    f16x2 v15 = *(const f16x2*)&Yc[(size_t)cidx[w][k + 15] * NC];
    f16x2 s0 = ((v0 + v1) + (v2 + v3)) + ((v4 + v5) + (v6 + v7));
    f16x2 s1 = ((v8 + v9) + (v10 + v11)) + ((v12 + v13) + (v14 + v15));
    a0 += (float)s0[0] + (float)s1[0];
    a1 += (float)s0[1] + (float)s1[1];
  }
  for (; k + 8 <= n; k += 8) {
    f16x2 v0 = *(const f16x2*)&Yc[(size_t)cidx[w][k + 0] * NC];
    f16x2 v1 = *(const f16x2*)&Yc[(size_t)cidx[w][k + 1] * NC];
    f16x2 v2 = *(const f16x2*)&Yc[(size_t)cidx[w][k + 2] * NC];
    f16x2 v3 = *(const f16x2*)&Yc[(size_t)cidx[w][k + 3] * NC];
    f16x2 v4 = *(const f16x2*)&Yc[(size_t)cidx[w][k + 4] * NC];
    f16x2 v5 = *(const f16x2*)&Yc[(size_t)cidx[w][k + 5] * NC];
    f16x2 v6 = *(const f16x2*)&Yc[(size_t)cidx[w][k + 6] * NC];
    f16x2 v7 = *(const f16x2*)&Yc[(size_t)cidx[w][k + 7] * NC];
    f16x2 s = ((v0 + v1) + (v2 + v3)) + ((v4 + v5) + (v6 + v7));
    a0 += (float)s[0];
    a1 += (float)s[1];
  }
  for (; k < n; ++k) {
    f16x2 v = *(const f16x2*)&Yc[(size_t)cidx[w][k] * NC];
    a0 += (float)v[0]; a1 += (float)v[1];
  }
  f16x2 vs = *(const f16x2*)&Yc[(size_t)row * NC];  // +I (eye)
  a0 += (float)vs[0]; a1 += (float)vs[1];
  const float di = dinv[row];
  float o0 = di * a0 + bias[cb];
  float o1 = di * a1 + bias[cb + 1];
  if (RELU) { o0 = fmaxf(o0, 0.f); o1 = fmaxf(o1, 0.f); }
  if constexpr (sizeof(OutT) == 4) {
    *(float2*)&out[(size_t)row * NC + cb] = make_float2(o0, o1);
  } else {
    f16x2 h = {(f16)o0, (f16)o1};
    *(f16x2*)&out[(size_t)row * NC + cb] = h;
  }
}

// ---------------------------------------------------------------------------
extern "C" void kernel_launch(void* const* d_in, const int* in_sizes, int n_in,
                              void* d_out, int out_size, void* d_ws, size_t ws_size,
                              hipStream_t stream) {
  const float* x  = (const float*)d_in[0];
  const int*   ei = (const int*)d_in[1];
  const float* W1 = (const float*)d_in[2];
  const float* b1 = (const float*)d_in[3];
  const float* W2 = (const float*)d_in[4];
  const float* b2 = (const float*)d_in[5];
  const float* W3 = (const float*)d_in[6];
  const float* b3 = (const float*)d_in[7];
  float* out = (float*)d_out;
  const int E = in_sizes[1] / 2;

  // Workspace (~29 MB). mask aliases Ys: mask dead after mask_to_csr, before
  // gemm1's first write to Ys.
  uint8_t* ws = (uint8_t*)d_ws;
  size_t off = 0;
  uint16_t* cols = (uint16_t*)ws;            off += (size_t)CSTRIDE * NN * 2;  // 3 MB
  int*      nnz  = (int*)(ws + off);         off += (size_t)NN * 4;            // 32 KB
  float*    dinv = (float*)(ws + off);       off += (size_t)NN * 4;            // 32 KB
  f16*      Wt1  = (f16*)(ws + off);         off += (size_t)512 * 512 * 2;     // 512 KB
  f16*      Wt2  = (f16*)(ws + off);         off += (size_t)512 * 512 * 2;     // 512 KB
  f16*      Wt3  = (f16*)(ws + off);         off += (size_t)256 * 512 * 2;     // 256 KB
  f16*      Xh   = (f16*)(ws + off);         off += (size_t)NN * 512 * 2;      // 8 MB
  f16*      H    = (f16*)(ws + off);         off += (size_t)NN * 512 * 2;      // 8 MB
  f16*      Ys   = (f16*)(ws + off);                                           // 8 MB
  uint32_t* mask = (uint32_t*)Ys;                                              // alias

  // ws is poisoned 0xAA before every call -> rebuild adjacency every launch
  hipMemsetAsync(mask, 0, (size_t)NN * WPR * sizeof(uint32_t), stream);
  build_adj<<<(E + 255) / 256, 256, 0, stream>>>(ei, mask, E);
  mask_to_csr<<<NN / 4, 256, 0, stream>>>(mask, cols, nnz, dinv);
  prep_all<<<2688, 256, 0, stream>>>(W1, W2, W3, x, Wt1, Wt2, Wt3, Xh);

  // Layer 1: Ys = f16(dinv ⊙ (Xh@W1)); H = relu(dinv ⊙ ((A+I)·Ys) + b1) in f16
  gemm_panel<512><<<NN / 32, 256, 0, stream>>>(Xh, Wt1, dinv, Ys);
  spmm_csr<512, f16, true><<<(NN / 4) * 4, 256, 0, stream>>>(cols, nnz, dinv, Ys, b1, H);

  // Layer 2
  gemm_panel<512><<<NN / 32, 256, 0, stream>>>(H, Wt2, dinv, Ys);
  spmm_csr<512, f16, true><<<(NN / 4) * 4, 256, 0, stream>>>(cols, nnz, dinv, Ys, b2, H);

  // Layer 3 (no ReLU), fp32 -> d_out
  gemm_panel<256><<<NN / 32, 256, 0, stream>>>(H, Wt3, dinv, Ys);
  spmm_csr<256, float, false><<<(NN / 4) * 2, 256, 0, stream>>>(cols, nnz, dinv, Ys, b3, out);
}